// Round 1
// baseline (1330.969 us; speedup 1.0000x reference)
//
#include <hip/hip_runtime.h>
#include <cstdint>
#include <cstddef>

typedef unsigned short u16;
typedef unsigned int u32;
typedef __attribute__((ext_vector_type(8))) short bf16x8_t;   // 8 bf16 (4 VGPRs)
typedef float f32x4 __attribute__((ext_vector_type(4)));

#define BR 32768   // batch rows
#define GLOBAL_AS __attribute__((address_space(1)))
#define LDS_AS __attribute__((address_space(3)))

__device__ __forceinline__ u16 f2bf(float f) {         // RNE f32->bf16
  u32 u = __float_as_uint(f);
  u32 r = (u + 0x7fffu + ((u >> 16) & 1u)) >> 16;
  return (u16)r;
}
__device__ __forceinline__ float bf2f(u16 h) { return __uint_as_float(((u32)h) << 16); }

// ---------------------------------------------------------------------------
// Shared GEMM core: C[128x128] tile, BK=64, A [M,K] row-major, B given as
// B^T [N,K] row-major (both K-contiguous). 256 thr = 4 waves, wave quadrant
// 64x64, 4x4 fragments of mfma_f32_16x16x32_bf16. global_load_lds staging.
// ---------------------------------------------------------------------------
__device__ __forceinline__ void stage_tile(const u16* g, size_t lda, u16* lds, int tid) {
  // 128 rows x 64 cols bf16 = 16KB, linear LDS. 4 waves x 4 iters x 64 lanes x 16B.
  int w = tid >> 6, l = tid & 63;
#pragma unroll
  for (int i = 0; i < 4; ++i) {
    int chunk = i * 4 + w;                 // 1KB chunk id, wave-uniform
    int row = chunk * 8 + (l >> 3);        // 0..127
    int cole = (l & 7) * 8;                // element col (16B per lane)
    const u16* ga = g + (size_t)row * lda + cole;
    __builtin_amdgcn_global_load_lds((const GLOBAL_AS void*)ga,
                                     (LDS_AS void*)(lds + chunk * 512), 16, 0, 0);
  }
}

__device__ __forceinline__ void gemm_core(const u16* Ag, const u16* Bg, size_t lda, size_t ldb,
                                          int nk, u16* ldsA, u16* ldsB, f32x4 acc[4][4], int tid) {
  int l = tid & 63;
  int wr = (tid >> 7) & 1, wc = (tid >> 6) & 1;
  int ar = wr * 64 + (l & 15);     // A-frag row base (add m*16)
  int br = wc * 64 + (l & 15);     // B-frag col base (add n*16)
  int kg = (l >> 4) * 8;           // k-group within 32
  for (int kt = 0; kt < nk; ++kt) {
    stage_tile(Ag + (size_t)kt * 64, lda, ldsA, tid);
    stage_tile(Bg + (size_t)kt * 64, ldb, ldsB, tid);
    __syncthreads();
#pragma unroll
    for (int s = 0; s < 2; ++s) {
      bf16x8_t af[4], bfr[4];
#pragma unroll
      for (int m = 0; m < 4; ++m) af[m] = *(const bf16x8_t*)(ldsA + (ar + m * 16) * 64 + s * 32 + kg);
#pragma unroll
      for (int n = 0; n < 4; ++n) bfr[n] = *(const bf16x8_t*)(ldsB + (br + n * 16) * 64 + s * 32 + kg);
#pragma unroll
      for (int m = 0; m < 4; ++m)
#pragma unroll
        for (int n = 0; n < 4; ++n)
          acc[m][n] = __builtin_amdgcn_mfma_f32_16x16x32_bf16(af[m], bfr[n], acc[m][n], 0, 0, 0);
    }
    __syncthreads();
  }
}

// ---------------------------------------------------------------------------
// Stage kernels
// ---------------------------------------------------------------------------
__global__ void k_zero(float* p, size_t n) {
  for (size_t i = (size_t)blockIdx.x * blockDim.x + threadIdx.x; i < n; i += (size_t)gridDim.x * blockDim.x)
    p[i] = 0.0f;
}

__global__ void k_cvt(const float* __restrict__ src, u16* __restrict__ dst, size_t n4) {
  for (size_t i = (size_t)blockIdx.x * blockDim.x + threadIdx.x; i < n4; i += (size_t)gridDim.x * blockDim.x) {
    float4 v = ((const float4*)src)[i];
    ushort4 o;
    o.x = f2bf(v.x); o.y = f2bf(v.y); o.z = f2bf(v.z); o.w = f2bf(v.w);
    ((ushort4*)dst)[i] = o;
  }
}

// fc: h[w] = x_sel(w) @ W_w^T  (bias skipped: cancels exactly in BatchNorm)
__global__ __launch_bounds__(256) void k_fc(const u16* __restrict__ xbf, const u16* __restrict__ wbf,
                                            u16* __restrict__ h) {
  __shared__ u16 ldsA[128 * 64];
  __shared__ u16 ldsB[128 * 64];
  int tid = threadIdx.x;
  int mb = blockIdx.x, nb = blockIdx.y;
  int w = nb >> 2, ns = nb & 3;
  const int selA[9] = {0, 1, 1, 1, 2, 2, 2, 0, 0};  // which input feeds weight w
  const u16* Ag = xbf + (size_t)selA[w] * BR * 1024 + (size_t)mb * 128 * 1024;
  const u16* Bg = wbf + ((size_t)w * 512 + (size_t)ns * 128) * 1024;
  f32x4 z = {0.f, 0.f, 0.f, 0.f};
  f32x4 acc[4][4];
#pragma unroll
  for (int m = 0; m < 4; ++m)
#pragma unroll
    for (int n = 0; n < 4; ++n) acc[m][n] = z;
  gemm_core(Ag, Bg, 1024, 1024, 16, ldsA, ldsB, acc, tid);
  int l = tid & 63;
  int wr = (tid >> 7) & 1, wc = (tid >> 6) & 1;
  u16* outp = h + (size_t)w * BR * 512;
  int rbase = mb * 128 + wr * 64 + ((l >> 4) << 2);
  int cbase = ns * 128 + wc * 64 + (l & 15);
#pragma unroll
  for (int m = 0; m < 4; ++m)
#pragma unroll
    for (int r = 0; r < 4; ++r) {
      size_t ro = (size_t)(rbase + m * 16 + r) * 512 + cbase;
#pragma unroll
      for (int n = 0; n < 4; ++n) outp[ro + n * 16] = f2bf(acc[m][n][r]);
    }
}

// per-column sums / sumsq over the batch dim (h is bf16 [BR,512] per w)
__global__ void k_stats(const u16* __restrict__ h, float* __restrict__ sums, float* __restrict__ sumsq) {
  int w = blockIdx.y, t = threadIdx.x;
  const u16* hp = h + (size_t)w * BR * 512;
  size_t r0 = (size_t)blockIdx.x * 512;
  float s0 = 0, s1 = 0, q0 = 0, q1 = 0;
#pragma unroll 4
  for (int r = 0; r < 512; ++r) {
    u32 u = *(const u32*)(hp + (r0 + r) * 512 + t * 2);
    float lo = __uint_as_float(u << 16);
    float hi = __uint_as_float(u & 0xffff0000u);
    s0 += lo; q0 += lo * lo; s1 += hi; q1 += hi * hi;
  }
  atomicAdd(&sums[w * 512 + t * 2], s0);
  atomicAdd(&sums[w * 512 + t * 2 + 1], s1);
  atomicAdd(&sumsq[w * 512 + t * 2], q0);
  atomicAdd(&sumsq[w * 512 + t * 2 + 1], q1);
}

__global__ void k_finalize(const float* __restrict__ sums, const float* __restrict__ sumsq,
                           float* __restrict__ mean, float* __restrict__ rstd) {
  int i = blockIdx.x * 256 + threadIdx.x;
  if (i < 9 * 512) {
    float mu = sums[i] * (1.0f / 32768.0f);
    float var = sumsq[i] * (1.0f / 32768.0f) - mu * mu;
    mean[i] = mu;
    rstd[i] = rsqrtf(var + 1e-5f);
  }
}

// normalize+ReLU+transpose Q/K buffers -> [512][BR] (Q also * 1/32, exact in bf16)
__global__ void k_normT(const u16* __restrict__ h, const float* __restrict__ mean,
                        const float* __restrict__ rstd, const float* __restrict__ gam,
                        const float* __restrict__ bet, u16* __restrict__ qt, u16* __restrict__ ktb) {
  __shared__ u16 tile[64][66];
  int t = threadIdx.x;
  int rb = blockIdx.x, cb = blockIdx.y, q = blockIdx.z;
  int attn = q >> 1, isk = q & 1;
  int w = 3 * attn + isk;
  float scale = isk ? 1.0f : (1.0f / 32.0f);
  const u16* hp = h + (size_t)w * BR * 512;
  u16* dst = (isk ? ktb : qt) + (size_t)attn * 512 * BR;
  int tc = (t & 15) * 4, tr = t >> 4;
  int colg = cb * 64 + tc;
  float mu[4], rs[4], gg[4], bb[4];
#pragma unroll
  for (int j = 0; j < 4; ++j) {
    mu[j] = mean[w * 512 + colg + j];
    rs[j] = rstd[w * 512 + colg + j];
    gg[j] = gam[w * 512 + colg + j];
    bb[j] = bet[w * 512 + colg + j];
  }
#pragma unroll
  for (int i = 0; i < 4; ++i) {
    int row = i * 16 + tr;
    ushort4 u = *(const ushort4*)(hp + (size_t)(rb * 64 + row) * 512 + colg);
    u16 uv[4] = {u.x, u.y, u.z, u.w};
#pragma unroll
    for (int j = 0; j < 4; ++j) {
      float f = bf2f(uv[j]);
      float y = fmaxf((f - mu[j]) * rs[j] * gg[j] + bb[j], 0.0f) * scale;
      tile[row][tc + j] = f2bf(y);
    }
  }
  __syncthreads();
#pragma unroll
  for (int i = 0; i < 4; ++i) {
    int oc = i * 16 + tr;
    ushort4 v;
    v.x = tile[tc + 0][oc]; v.y = tile[tc + 1][oc];
    v.z = tile[tc + 2][oc]; v.w = tile[tc + 3][oc];
    *(ushort4*)(dst + (size_t)(cb * 64 + oc) * BR + rb * 64 + tc) = v;
  }
}

// normalize+ReLU V buffers in place ([BR,512])
__global__ void k_normv(u16* __restrict__ h, const float* __restrict__ mean,
                        const float* __restrict__ rstd, const float* __restrict__ gam,
                        const float* __restrict__ bet) {
  int w = 3 * blockIdx.y + 2;
  u16* hp = h + (size_t)w * BR * 512;
  const float* mu = mean + w * 512;
  const float* rs = rstd + w * 512;
  const float* gg = gam + w * 512;
  const float* bb = bet + w * 512;
  const size_t n4 = (size_t)BR * 512 / 4;
  for (size_t i = (size_t)blockIdx.x * blockDim.x + threadIdx.x; i < n4; i += (size_t)gridDim.x * blockDim.x) {
    int col = (int)((i * 4) & 511);
    ushort4 v = ((const ushort4*)hp)[i];
    u16 uv[4] = {v.x, v.y, v.z, v.w};
    ushort4 o;
    u16 ov[4];
#pragma unroll
    for (int j = 0; j < 4; ++j) {
      float f = bf2f(uv[j]);
      ov[j] = f2bf(fmaxf((f - mu[col + j]) * rs[col + j] * gg[col + j] + bb[col + j], 0.0f));
    }
    o.x = ov[0]; o.y = ov[1]; o.z = ov[2]; o.w = ov[3];
    ((ushort4*)hp)[i] = o;
  }
}

// S[a][i][j] += sum_b Q^T[i,b] * K^T[j,b]  (split-K 16-way, fp32 atomics; Q pre-scaled 1/32)
__global__ __launch_bounds__(256) void k_qk(const u16* __restrict__ qt, const u16* __restrict__ ktb,
                                            float* __restrict__ S) {
  __shared__ u16 ldsA[128 * 64];
  __shared__ u16 ldsB[128 * 64];
  int tid = threadIdx.x;
  int a = blockIdx.z >> 4, ks = blockIdx.z & 15;
  const u16* Ag = qt + ((size_t)a * 512 + (size_t)blockIdx.x * 128) * BR + (size_t)ks * 2048;
  const u16* Bg = ktb + ((size_t)a * 512 + (size_t)blockIdx.y * 128) * BR + (size_t)ks * 2048;
  f32x4 z = {0.f, 0.f, 0.f, 0.f};
  f32x4 acc[4][4];
#pragma unroll
  for (int m = 0; m < 4; ++m)
#pragma unroll
    for (int n = 0; n < 4; ++n) acc[m][n] = z;
  gemm_core(Ag, Bg, BR, BR, 32, ldsA, ldsB, acc, tid);
  int l = tid & 63;
  int wr = (tid >> 7) & 1, wc = (tid >> 6) & 1;
  float* Sp = S + (size_t)a * 512 * 512;
  int rbase = blockIdx.x * 128 + wr * 64 + ((l >> 4) << 2);
  int cbase = blockIdx.y * 128 + wc * 64 + (l & 15);
#pragma unroll
  for (int m = 0; m < 4; ++m)
#pragma unroll
    for (int r = 0; r < 4; ++r)
#pragma unroll
      for (int n = 0; n < 4; ++n)
        atomicAdd(&Sp[(size_t)(rbase + m * 16 + r) * 512 + cbase + n * 16], acc[m][n][r]);
}

// row softmax over S [1536 rows of 512], write bf16 attn (row-major [i][j])
__global__ void k_softmax(const float* __restrict__ S, u16* __restrict__ attnb) {
  const float* sp = S + (size_t)blockIdx.x * 512;
  int l = threadIdx.x;
  float4 v0 = ((const float4*)sp)[l * 2];
  float4 v1 = ((const float4*)sp)[l * 2 + 1];
  float vv[8] = {v0.x, v0.y, v0.z, v0.w, v1.x, v1.y, v1.z, v1.w};
  float mx = vv[0];
#pragma unroll
  for (int j = 1; j < 8; ++j) mx = fmaxf(mx, vv[j]);
#pragma unroll
  for (int m = 32; m >= 1; m >>= 1) mx = fmaxf(mx, __shfl_xor(mx, m, 64));
  float s = 0.f;
#pragma unroll
  for (int j = 0; j < 8; ++j) { vv[j] = __expf(vv[j] - mx); s += vv[j]; }
#pragma unroll
  for (int m = 32; m >= 1; m >>= 1) s += __shfl_xor(s, m, 64);
  float inv = 1.0f / s;
  u16* op = attnb + (size_t)blockIdx.x * 512 + l * 8;
  ushort4 o0, o1;
  o0.x = f2bf(vv[0] * inv); o0.y = f2bf(vv[1] * inv); o0.z = f2bf(vv[2] * inv); o0.w = f2bf(vv[3] * inv);
  o1.x = f2bf(vv[4] * inv); o1.y = f2bf(vv[5] * inv); o1.z = f2bf(vv[6] * inv); o1.w = f2bf(vv[7] * inv);
  ((ushort4*)op)[0] = o0;
  ((ushort4*)op)[1] = o1;
}

// out[a] = V_a @ attn_a^T   (attn row-major [i][j] IS the B^T layout)
__global__ __launch_bounds__(256) void k_out(const u16* __restrict__ h, const u16* __restrict__ attnb,
                                             float* __restrict__ outp) {
  __shared__ u16 ldsA[128 * 64];
  __shared__ u16 ldsB[128 * 64];
  int tid = threadIdx.x;
  int a = blockIdx.z;
  const u16* Ag = h + (size_t)(3 * a + 2) * BR * 512 + (size_t)blockIdx.x * 128 * 512;
  const u16* Bg = attnb + (size_t)a * 512 * 512 + (size_t)blockIdx.y * 128 * 512;
  f32x4 z = {0.f, 0.f, 0.f, 0.f};
  f32x4 acc[4][4];
#pragma unroll
  for (int m = 0; m < 4; ++m)
#pragma unroll
    for (int n = 0; n < 4; ++n) acc[m][n] = z;
  gemm_core(Ag, Bg, 512, 512, 8, ldsA, ldsB, acc, tid);
  int l = tid & 63;
  int wr = (tid >> 7) & 1, wc = (tid >> 6) & 1;
  float* op = outp + (size_t)a * BR * 512;
  int rbase = blockIdx.x * 128 + wr * 64 + ((l >> 4) << 2);
  int cbase = blockIdx.y * 128 + wc * 64 + (l & 15);
#pragma unroll
  for (int m = 0; m < 4; ++m)
#pragma unroll
    for (int r = 0; r < 4; ++r) {
      size_t ro = (size_t)(rbase + m * 16 + r) * 512 + cbase;
#pragma unroll
      for (int n = 0; n < 4; ++n) op[ro + n * 16] = acc[m][n][r];
    }
}

// ---------------------------------------------------------------------------
extern "C" void kernel_launch(void* const* d_in, const int* in_sizes, int n_in,
                              void* d_out, int out_size, void* d_ws, size_t ws_size,
                              hipStream_t stream) {
  const float* cx = (const float*)d_in[0];
  const float* gx = (const float*)d_in[1];
  const float* wx = (const float*)d_in[2];
  const float* Ws = (const float*)d_in[3];
  // d_in[4] = bs : bias cancels exactly in BatchNorm -> unused
  const float* gammas = (const float*)d_in[5];
  const float* betas = (const float*)d_in[6];
  float* outp = (float*)d_out;

  char* ws = (char*)d_ws;
  const size_t B = BR;
  // layout (xbf region later reused for Q^T/K^T)
  u16* xbf = (u16*)ws;                                  // 3*B*1024 bf16 = 192 MiB
  u16* qt = xbf;                                        // 3*512*B bf16 = 96 MiB (after fc)
  u16* ktb = xbf + (size_t)3 * 512 * B;                 // 96 MiB
  u16* wbf = (u16*)(ws + (size_t)3 * B * 1024 * 2);     // 9 MiB
  u16* h = wbf + (size_t)9 * 512 * 1024;                // 9*B*512 bf16 = 288 MiB
  float* S = (float*)((char*)h + (size_t)9 * B * 512 * 2);      // 3 MiB
  u16* attnb = (u16*)((char*)S + (size_t)3 * 512 * 512 * 4);    // 1.5 MiB
  float* sums = (float*)((char*)attnb + (size_t)3 * 512 * 512 * 2);
  float* sumsq = sums + 9 * 512;
  float* mean = sumsq + 9 * 512;
  float* rstd = mean + 9 * 512;

  k_zero<<<64, 256, 0, stream>>>(S, (size_t)3 * 512 * 512);
  k_zero<<<8, 256, 0, stream>>>(sums, (size_t)2 * 9 * 512);

  k_cvt<<<2048, 256, 0, stream>>>(cx, xbf, (size_t)B * 1024 / 4);
  k_cvt<<<2048, 256, 0, stream>>>(gx, xbf + (size_t)B * 1024, (size_t)B * 1024 / 4);
  k_cvt<<<2048, 256, 0, stream>>>(wx, xbf + (size_t)2 * B * 1024, (size_t)B * 1024 / 4);
  k_cvt<<<1024, 256, 0, stream>>>(Ws, wbf, (size_t)9 * 512 * 1024 / 4);

  k_fc<<<dim3(256, 36), 256, 0, stream>>>(xbf, wbf, h);
  k_stats<<<dim3(64, 9), 256, 0, stream>>>(h, sums, sumsq);
  k_finalize<<<18, 256, 0, stream>>>(sums, sumsq, mean, rstd);
  k_normT<<<dim3(512, 8, 6), 256, 0, stream>>>(h, mean, rstd, gammas, betas, qt, ktb);
  k_normv<<<dim3(2048, 3), 256, 0, stream>>>(h, mean, rstd, gammas, betas);
  k_qk<<<dim3(4, 4, 48), 256, 0, stream>>>(qt, ktb, S);
  k_softmax<<<1536, 64, 0, stream>>>(S, attnb);
  k_out<<<dim3(256, 4, 3), 256, 0, stream>>>(h, attnb, outp);
}